// Round 10
// baseline (299.277 us; speedup 1.0000x reference)
//
#include <hip/hip_runtime.h>
#include <hip/hip_bf16.h>

#define EPSF 1e-14f
#define RHOF 8.0f

typedef __attribute__((ext_vector_type(4))) float f32x4;
typedef __attribute__((ext_vector_type(8))) int   i32x8;

#define AS_GLOBAL __attribute__((address_space(1)))
#define AS_LDS    __attribute__((address_space(3)))

// fp8 packed layout, BK=128 (for mfma_scale 16x16x128). Tile = 128 rows x
// 128 cols fp8 = 16 KB = 1024 units of 16 B. Row r = 8 units; content unit
// u stored at slot u ^ (r&7). Fragment (quad qd) needs k-block qd*32..+31 =
// content units {2qd, 2qd+1} -> slots s0=(2qd)^(lo&7), s0^1.
// global_load_lds deposit order == packed order.

// One-pass prep: thread reads 16 contiguous fp32 (64 B), cvt_pk to 16 fp8,
// one 16-B store to the packed slot address. No LDS, no barrier.
__global__ __launch_bounds__(256) void prep_fp8(
    const float* __restrict__ im,  const float* __restrict__ tt,
    const float* __restrict__ rim, const float* __restrict__ rtt,
    unsigned char* __restrict__ bIm,  unsigned char* __restrict__ bTt,
    unsigned char* __restrict__ bRim, unsigned char* __restrict__ bRtt,
    float* __restrict__ S_im, float* __restrict__ S_tt,
    float* __restrict__ diag, float* __restrict__ red,
    int D, int bpm /* conversion blocks per matrix */)
{
    const int b = blockIdx.x;
    const int tid = threadIdx.x;
    const int nConv = 4 * bpm;
    if (b < nConv) {
        int mIdx = b / bpm;
        int blk  = b - mIdx * bpm;
        const float* src = (mIdx == 0) ? rim : (mIdx == 1) ? tt
                          : (mIdx == 2) ? rtt : im;
        unsigned char* dst = (mIdx == 0) ? bRim : (mIdx == 1) ? bTt
                            : (mIdx == 2) ? bRtt : bIm;
        const int upr = D >> 4;            // 16-B content units per row
        const int rpb = 256 / upr;         // rows per block (D=1024 -> 4)
        const int urow = tid / upr;
        const int c    = tid - urow * upr; // content unit within row
        const int r    = blk * rpb + urow;
        const int kTiles = D >> 7;
        const float* p = src + (size_t)r * D + (size_t)c * 16;
        float4 v0 = ((const float4*)p)[0];
        float4 v1 = ((const float4*)p)[1];
        float4 v2 = ((const float4*)p)[2];
        float4 v3 = ((const float4*)p)[3];
        int w0 = __builtin_amdgcn_cvt_pk_fp8_f32(v0.x, v0.y, 0, false);
        w0     = __builtin_amdgcn_cvt_pk_fp8_f32(v0.z, v0.w, w0, true);
        int w1 = __builtin_amdgcn_cvt_pk_fp8_f32(v1.x, v1.y, 0, false);
        w1     = __builtin_amdgcn_cvt_pk_fp8_f32(v1.z, v1.w, w1, true);
        int w2 = __builtin_amdgcn_cvt_pk_fp8_f32(v2.x, v2.y, 0, false);
        w2     = __builtin_amdgcn_cvt_pk_fp8_f32(v2.z, v2.w, w2, true);
        int w3 = __builtin_amdgcn_cvt_pk_fp8_f32(v3.x, v3.y, 0, false);
        w3     = __builtin_amdgcn_cvt_pk_fp8_f32(v3.z, v3.w, w3, true);
        int4 out = make_int4(w0, w1, w2, w3);
        const int kb = c >> 3;
        const int p8 = (c & 7) ^ (r & 7);          // XOR slot
        *(int4*)(dst + ((size_t)((r >> 7) * kTiles + kb) * 1024
                        + (size_t)(r & 127) * 8 + p8) * 16) = out;
    } else {
        int db = b - nConv;
        if (db == 0 && tid < 8) red[tid] = 0.f;
        if (tid < 4) { S_im[db * 4 + tid] = 0.f; S_tt[db * 4 + tid] = 0.f; }
        int row  = db * 4 + (tid >> 6);
        int lane = tid & 63;
        const float* a = rim + (size_t)row * D;
        const float* c2 = rtt + (size_t)row * D;
        float s = 0.f;
        for (int k = lane * 4; k < D; k += 256) {
            float4 av = *(const float4*)(a + k);
            float4 cv = *(const float4*)(c2 + k);
            s += av.x * cv.x + av.y * cv.y + av.z * cv.z + av.w * cv.w;
        }
        #pragma unroll
        for (int m2 = 1; m2 < 64; m2 <<= 1) s += __shfl_xor(s, m2, 64);
        if (lane == 0) diag[row] = s;
    }
}

// MX-scaled fp8 GEMM -- m148-style 128x128 tile, 4 waves (2x2 of 64x64),
// BK=128, single-buffered 32 KiB LDS, plain __syncthreads() 2-barrier loop.
// __launch_bounds__(256,4): cap unified VGPR+AGPR at 128 -> 4 blocks/CU
// co-resident (cross-block implicit latency overlap, the m97/m148 regime).
// FUSED final reduction: after the epilogue each block increments a
// device-scope ticket; the last block (release-acquire via threadfence +
// atomic) computes the scalar loss in-block. Saves a launch + drain/fill.
__global__ __launch_bounds__(256, 4) void gemm_expsum(
    const unsigned char* __restrict__ A0, const unsigned char* __restrict__ B0,
    float* __restrict__ S0,
    const unsigned char* __restrict__ A1, const unsigned char* __restrict__ B1,
    float* __restrict__ S1,
    const float* __restrict__ logit_scale, const int* __restrict__ offset,
    const float* __restrict__ diag,
    const float* __restrict__ ru_im, const float* __restrict__ ru_tt,
    const float* __restrict__ l1_im, const float* __restrict__ l1_tt,
    const float* __restrict__ u_im,  const float* __restrict__ u_tt,
    float* __restrict__ red, float* __restrict__ out,
    int Bn, int D)
{
    __shared__ unsigned char As[16384];
    __shared__ unsigned char Bs[16384];
    __shared__ int lastFlag;

    const int z = blockIdx.z;
    const unsigned char* A = z ? A1 : A0;
    const unsigned char* B = z ? B1 : B0;
    float* S = z ? S1 : S0;

    const int tid  = threadIdx.x;
    const int wave = tid >> 6;
    const int lane = tid & 63;
    const int lo   = lane & 15;
    const int qd   = lane >> 4;
    const int wm   = wave >> 1;              // 0..1  (M half, 64 rows)
    const int wn   = wave & 1;               // 0..1  (N half, 64 cols)
    const int offA = ((2 * qd) ^ (lo & 7)) * 16;   // first 16-B slot

    // XCD-bijective swizzle per z-plane (nwg = 1024, % 8 == 0).
    const int nx  = gridDim.x;
    const int nwg = nx * gridDim.y;
    int wg = blockIdx.y * nx + blockIdx.x;
    int swz = ((nwg & 7) == 0) ? ((wg & 7) * (nwg >> 3) + (wg >> 3)) : wg;
    const int by = swz / nx;
    const int bx = swz - by * nx;

    const int kTiles = D >> 7;
    const unsigned char* Atile = A + (size_t)by * kTiles * 16384;
    const unsigned char* Btile = B + (size_t)bx * kTiles * 16384;

    f32x4 acc[4][4];
    #pragma unroll
    for (int i = 0; i < 4; ++i)
        #pragma unroll
        for (int j = 0; j < 4; ++j)
            acc[i][j] = (f32x4){0.f, 0.f, 0.f, 0.f};

    // per-lane LDS fragment bases (r&7 == lo&7 for all ti/tj)
    const int aOff0 = (wm * 64 + lo) * 128 + offA;   // + ti*2048
    const int bOff0 = (wn * 64 + lo) * 128 + offA;   // + tj*2048

    for (int kb = 0; kb < kTiles; ++kb) {
        // Stage A+B tile kb (16 KB each): 4 waves x 4 DMA x 1 KB per matrix.
        {
            const unsigned char* Ag = Atile + (size_t)kb * 16384
                                    + wave * 4096 + lane * 16;
            const unsigned char* Bg = Btile + (size_t)kb * 16384
                                    + wave * 4096 + lane * 16;
            #pragma unroll
            for (int q = 0; q < 4; ++q) {
                __builtin_amdgcn_global_load_lds(
                    (const AS_GLOBAL unsigned int*)(Ag + q * 1024),
                    (AS_LDS unsigned int*)&As[wave * 4096 + q * 1024],
                    16, 0, 0);
                __builtin_amdgcn_global_load_lds(
                    (const AS_GLOBAL unsigned int*)(Bg + q * 1024),
                    (AS_LDS unsigned int*)&Bs[wave * 4096 + q * 1024],
                    16, 0, 0);
            }
        }
        __syncthreads();           // compiler drains vmcnt before barrier

        i32x8 bq[4];
        #pragma unroll
        for (int tj = 0; tj < 4; ++tj) {
            const int ba = bOff0 + tj * 2048;
            union { int4 h[2]; i32x8 v; } u;
            u.h[0] = *(const int4*)&Bs[ba];
            u.h[1] = *(const int4*)&Bs[ba ^ 16];
            bq[tj] = u.v;
        }
        #pragma unroll
        for (int ti = 0; ti < 4; ++ti) {
            const int aa = aOff0 + ti * 2048;
            union { int4 h[2]; i32x8 v; } u;
            u.h[0] = *(const int4*)&As[aa];
            u.h[1] = *(const int4*)&As[aa ^ 16];
            i32x8 af = u.v;
            #pragma unroll
            for (int tj = 0; tj < 4; ++tj)
                acc[ti][tj] = __builtin_amdgcn_mfma_scale_f32_16x16x128_f8f6f4(
                    af, bq[tj], acc[ti][tj],
                    0, 0,          // cbsz=fp8(e4m3), blgp=fp8(e4m3)
                    0, 127,        // scale A: E8M0 127 = x1.0
                    0, 127);       // scale B
        }
        __syncthreads();           // done with LDS before next stage
    }

    const float ls = logit_scale[0];
    const int offs = offset[0];
    const int rowBase = by * 128 + wm * 64;
    const int colBase = bx * 128 + wn * 64;
    #pragma unroll
    for (int ti = 0; ti < 4; ++ti) {
        #pragma unroll
        for (int r = 0; r < 4; ++r) {
            int gi = rowBase + 16 * ti + 4 * qd + r;     // C/D row=quad*4+reg
            float rs = 0.f;
            #pragma unroll
            for (int tj = 0; tj < 4; ++tj) {
                int gj = colBase + 16 * tj + lo;         // C/D col=lane&15
                float e = __expf(ls * acc[ti][tj][r]);
                if (gj == gi + offs) e = 0.f;            // shifted diagonal
                rs += e;
            }
            #pragma unroll
            for (int m = 1; m < 16; m <<= 1) rs += __shfl_xor(rs, m, 64);
            if (lo == 0) atomicAdd(&S[gi], rs);
        }
    }

    // ---- fused final reduction (ticket: last block does it all) ----
    __threadfence();                         // release our S atomics
    if (tid == 0) {
        int t = atomicAdd((int*)&red[2], 1);
        lastFlag = (t == (int)(gridDim.x * gridDim.y * gridDim.z) - 1);
    }
    __syncthreads();
    if (!lastFlag) return;
    __threadfence();                         // acquire all blocks' S writes

    const float inv_rw = 1.0f / (float)(Bn - 1);
    float pg = 0.f, lg = 0.f;
    for (int i = tid; i < Bn; i += 256) {
        float p1 = l1_im[i] / (u_im[i] + EPSF) + l1_tt[i] / (u_tt[i] + EPSF);
        float dd = expf(-ls * diag[i]);
        float p2 = dd * S0[i] * inv_rw / (ru_im[i] + EPSF)
                 + dd * S1[i] * inv_rw / (ru_tt[i] + EPSF);
        pg += p1 + p2;
        lg += logf(u_im[i]) + logf(u_tt[i]);
    }
    float* sp = (float*)As;                  // LDS free after K-loop
    float* sl = sp + 256;
    sp[tid] = pg; sl[tid] = lg;
    __syncthreads();
    for (int s = 128; s > 0; s >>= 1) {
        if (tid < s) { sp[tid] += sp[tid + s]; sl[tid] += sl[tid + s]; }
        __syncthreads();
    }
    if (tid == 0) {
        float loss = ((sp[0] / (float)Bn) * 0.5f) / ls
                   + RHOF / ls
                   + (sl[0] / (float)Bn) * 0.5f / ls;
        out[0] = loss;
    }
}

extern "C" void kernel_launch(void* const* d_in, const int* in_sizes, int n_in,
                              void* d_out, int out_size, void* d_ws, size_t ws_size,
                              hipStream_t stream) {
    const float* im    = (const float*)d_in[0];
    const float* tt    = (const float*)d_in[1];
    const float* rim   = (const float*)d_in[2];
    const float* rtt   = (const float*)d_in[3];
    const float* ru_im = (const float*)d_in[4];
    const float* ru_tt = (const float*)d_in[5];
    const float* l1_im = (const float*)d_in[6];
    const float* l1_tt = (const float*)d_in[7];
    const float* u_im  = (const float*)d_in[8];
    const float* u_tt  = (const float*)d_in[9];
    const float* lsc   = (const float*)d_in[10];
    const int*   offs  = (const int*)d_in[11];

    const int Bn = in_sizes[4];          // 4096
    const int D  = in_sizes[0] / Bn;     // 1024
    const int rpb = 4096 / D;            // rows per conversion block
    const int bpm = Bn / rpb;            // conversion blocks per matrix

    char* base = (char*)d_ws;
    float* S_im = (float*)base;
    float* S_tt = S_im + Bn;
    float* diag = S_tt + Bn;
    float* red  = diag + Bn;             // [0]=unused, [1]=unused, [2]=ticket
    const size_t headBytes = (((size_t)(3 * Bn + 8) * sizeof(float)) + 255) & ~(size_t)255;
    const size_t matBytes  = (size_t)Bn * D;          // fp8: 1 B/elem
    unsigned char* buf0 = (unsigned char*)(base + headBytes);
    unsigned char* bRim = buf0;
    unsigned char* bTt  = buf0 + matBytes;
    unsigned char* bRtt = buf0 + 2 * matBytes;
    unsigned char* bIm  = buf0 + 3 * matBytes;

    prep_fp8<<<4 * bpm + Bn / 4, 256, 0, stream>>>(
        im, tt, rim, rtt, bIm, bTt, bRim, bRtt, S_im, S_tt, diag, red, D, bpm);

    dim3 ggrid(Bn / 128, Bn / 128, 2);
    gemm_expsum<<<ggrid, 256, 0, stream>>>(
        bRim, bTt, S_im, bRtt, bIm, S_tt, lsc, offs,
        diag, ru_im, ru_tt, l1_im, l1_tt, u_im, u_tt,
        red, (float*)d_out, Bn, D);
}

// Round 11
// 285.390 us; speedup vs baseline: 1.0487x; 1.0487x over previous
//
#include <hip/hip_runtime.h>
#include <hip/hip_bf16.h>

#define EPSF 1e-14f
#define RHOF 8.0f

typedef __attribute__((ext_vector_type(4))) float f32x4;
typedef __attribute__((ext_vector_type(8))) int   i32x8;

#define AS_GLOBAL __attribute__((address_space(1)))
#define AS_LDS    __attribute__((address_space(3)))

// fp8 packed layout, BK=128 (for mfma_scale 16x16x128). Tile = 128 rows x
// 128 cols fp8 = 16 KB = 1024 units of 16 B. Row r = 8 units; content unit
// u stored at slot u ^ (r&7). Fragment (quad qd) needs k-block qd*32..+31 =
// content units {2qd, 2qd+1} -> slots s0=(2qd)^(lo&7), s0^1.
// global_load_lds deposit order == packed order.

// One-pass prep with FUSED diag:
//  - blocks [0, nComb):   rim+rtt combined. 128 threads rim (2 rows x 64
//    units) + 128 threads rtt. Convert+store both; rim threads park fp32 in
//    LDS, rtt threads dot against it -> diag. Saves the 32 MB diag re-read.
//  - blocks [nComb, +bpm): im conversion (4 rows/block).
//  - blocks [+bpm, +2bpm): tt conversion.
__global__ __launch_bounds__(256) void prep_fp8(
    const float* __restrict__ im,  const float* __restrict__ tt,
    const float* __restrict__ rim, const float* __restrict__ rtt,
    unsigned char* __restrict__ bIm,  unsigned char* __restrict__ bTt,
    unsigned char* __restrict__ bRim, unsigned char* __restrict__ bRtt,
    float* __restrict__ S_im, float* __restrict__ S_tt,
    float* __restrict__ diag, float* __restrict__ red,
    int D, int nComb, int bpm)
{
    const int b = blockIdx.x;
    const int tid = threadIdx.x;
    const int kTiles = D >> 7;

    if (b < nComb) {
        // ---- combined rim+rtt: 2 rows, convert + diag ----
        __shared__ float4 Lf[2][72][4];          // padded: slot c+(c>>3)
        const int half = tid >> 7;               // 0 = rim, 1 = rtt
        const int t2   = tid & 127;
        const int urow = t2 >> 6;
        const int c    = t2 & 63;                // unit within row (D=1024)
        const int r    = b * 2 + urow;
        const float* src = half ? rtt : rim;
        unsigned char* dst = half ? bRtt : bRim;

        const float* p = src + (size_t)r * D + (size_t)c * 16;
        float4 v0 = ((const float4*)p)[0];
        float4 v1 = ((const float4*)p)[1];
        float4 v2 = ((const float4*)p)[2];
        float4 v3 = ((const float4*)p)[3];
        int w0 = __builtin_amdgcn_cvt_pk_fp8_f32(v0.x, v0.y, 0, false);
        w0     = __builtin_amdgcn_cvt_pk_fp8_f32(v0.z, v0.w, w0, true);
        int w1 = __builtin_amdgcn_cvt_pk_fp8_f32(v1.x, v1.y, 0, false);
        w1     = __builtin_amdgcn_cvt_pk_fp8_f32(v1.z, v1.w, w1, true);
        int w2 = __builtin_amdgcn_cvt_pk_fp8_f32(v2.x, v2.y, 0, false);
        w2     = __builtin_amdgcn_cvt_pk_fp8_f32(v2.z, v2.w, w2, true);
        int w3 = __builtin_amdgcn_cvt_pk_fp8_f32(v3.x, v3.y, 0, false);
        w3     = __builtin_amdgcn_cvt_pk_fp8_f32(v3.z, v3.w, w3, true);
        int4 out = make_int4(w0, w1, w2, w3);
        const int kb = c >> 3;
        const int p8 = (c & 7) ^ (r & 7);        // XOR slot
        *(int4*)(dst + ((size_t)((r >> 7) * kTiles + kb) * 1024
                        + (size_t)(r & 127) * 8 + p8) * 16) = out;

        const int cs = c + (c >> 3);             // padded LDS slot
        if (!half) {
            Lf[urow][cs][0] = v0; Lf[urow][cs][1] = v1;
            Lf[urow][cs][2] = v2; Lf[urow][cs][3] = v3;
        }
        // zero S arrays / ticket (2048 blocks x 2 rows cover 4096)
        if (tid < 2) { S_im[b * 2 + tid] = 0.f; S_tt[b * 2 + tid] = 0.f; }
        if (b == 0 && tid >= 8 && tid < 16) red[tid - 8] = 0.f;
        __syncthreads();
        if (half) {
            float4 a0 = Lf[urow][cs][0], a1 = Lf[urow][cs][1];
            float4 a2 = Lf[urow][cs][2], a3 = Lf[urow][cs][3];
            float s = a0.x*v0.x + a0.y*v0.y + a0.z*v0.z + a0.w*v0.w
                    + a1.x*v1.x + a1.y*v1.y + a1.z*v1.z + a1.w*v1.w
                    + a2.x*v2.x + a2.y*v2.y + a2.z*v2.z + a2.w*v2.w
                    + a3.x*v3.x + a3.y*v3.y + a3.z*v3.z + a3.w*v3.w;
            #pragma unroll
            for (int m2 = 1; m2 < 64; m2 <<= 1) s += __shfl_xor(s, m2, 64);
            if (c == 0) diag[r] = s;             // lane 0 of the row's wave
        }
    } else {
        // ---- im / tt conversion-only: 4 rows/block ----
        int b2 = b - nComb;
        const int isTT = (b2 >= bpm);
        const int blk  = isTT ? b2 - bpm : b2;
        const float* src = isTT ? tt : im;
        unsigned char* dst = isTT ? bTt : bIm;
        const int upr = D >> 4;                  // 64 units per row
        const int urow = tid / upr;
        const int c    = tid - urow * upr;
        const int r    = blk * (256 / upr) + urow;
        const float* p = src + (size_t)r * D + (size_t)c * 16;
        float4 v0 = ((const float4*)p)[0];
        float4 v1 = ((const float4*)p)[1];
        float4 v2 = ((const float4*)p)[2];
        float4 v3 = ((const float4*)p)[3];
        int w0 = __builtin_amdgcn_cvt_pk_fp8_f32(v0.x, v0.y, 0, false);
        w0     = __builtin_amdgcn_cvt_pk_fp8_f32(v0.z, v0.w, w0, true);
        int w1 = __builtin_amdgcn_cvt_pk_fp8_f32(v1.x, v1.y, 0, false);
        w1     = __builtin_amdgcn_cvt_pk_fp8_f32(v1.z, v1.w, w1, true);
        int w2 = __builtin_amdgcn_cvt_pk_fp8_f32(v2.x, v2.y, 0, false);
        w2     = __builtin_amdgcn_cvt_pk_fp8_f32(v2.z, v2.w, w2, true);
        int w3 = __builtin_amdgcn_cvt_pk_fp8_f32(v3.x, v3.y, 0, false);
        w3     = __builtin_amdgcn_cvt_pk_fp8_f32(v3.z, v3.w, w3, true);
        int4 out = make_int4(w0, w1, w2, w3);
        const int kb = c >> 3;
        const int p8 = (c & 7) ^ (r & 7);
        *(int4*)(dst + ((size_t)((r >> 7) * kTiles + kb) * 1024
                        + (size_t)(r & 127) * 8 + p8) * 16) = out;
    }
}

// MX-scaled fp8 GEMM -- m148-style 128x128 tile, 4 waves (2x2 of 64x64),
// BK=128, single-buffered 32 KiB LDS, plain __syncthreads() 2-barrier loop.
// __launch_bounds__(256) ONLY -- r10 proved a (,4) reg cap strangles the
// inner-loop ILP (MfmaUtil 22% -> 7%); let the allocator use ~136 regs.
// FUSED final reduction via device-scope ticket (r10-verified correct).
__global__ __launch_bounds__(256) void gemm_expsum(
    const unsigned char* __restrict__ A0, const unsigned char* __restrict__ B0,
    float* __restrict__ S0,
    const unsigned char* __restrict__ A1, const unsigned char* __restrict__ B1,
    float* __restrict__ S1,
    const float* __restrict__ logit_scale, const int* __restrict__ offset,
    const float* __restrict__ diag,
    const float* __restrict__ ru_im, const float* __restrict__ ru_tt,
    const float* __restrict__ l1_im, const float* __restrict__ l1_tt,
    const float* __restrict__ u_im,  const float* __restrict__ u_tt,
    float* __restrict__ red, float* __restrict__ out,
    int Bn, int D)
{
    __shared__ unsigned char As[16384];
    __shared__ unsigned char Bs[16384];
    __shared__ int lastFlag;

    const int z = blockIdx.z;
    const unsigned char* A = z ? A1 : A0;
    const unsigned char* B = z ? B1 : B0;
    float* S = z ? S1 : S0;

    const int tid  = threadIdx.x;
    const int wave = tid >> 6;
    const int lane = tid & 63;
    const int lo   = lane & 15;
    const int qd   = lane >> 4;
    const int wm   = wave >> 1;              // 0..1  (M half, 64 rows)
    const int wn   = wave & 1;               // 0..1  (N half, 64 cols)
    const int offA = ((2 * qd) ^ (lo & 7)) * 16;   // first 16-B slot

    // XCD-bijective swizzle per z-plane (nwg = 1024, % 8 == 0).
    const int nx  = gridDim.x;
    const int nwg = nx * gridDim.y;
    int wg = blockIdx.y * nx + blockIdx.x;
    int swz = ((nwg & 7) == 0) ? ((wg & 7) * (nwg >> 3) + (wg >> 3)) : wg;
    const int by = swz / nx;
    const int bx = swz - by * nx;

    const int kTiles = D >> 7;
    const unsigned char* Atile = A + (size_t)by * kTiles * 16384;
    const unsigned char* Btile = B + (size_t)bx * kTiles * 16384;

    f32x4 acc[4][4];
    #pragma unroll
    for (int i = 0; i < 4; ++i)
        #pragma unroll
        for (int j = 0; j < 4; ++j)
            acc[i][j] = (f32x4){0.f, 0.f, 0.f, 0.f};

    // per-lane LDS fragment bases (r&7 == lo&7 for all ti/tj)
    const int aOff0 = (wm * 64 + lo) * 128 + offA;   // + ti*2048
    const int bOff0 = (wn * 64 + lo) * 128 + offA;   // + tj*2048

    for (int kb = 0; kb < kTiles; ++kb) {
        // Stage A+B tile kb (16 KB each): 4 waves x 4 DMA x 1 KB per matrix.
        {
            const unsigned char* Ag = Atile + (size_t)kb * 16384
                                    + wave * 4096 + lane * 16;
            const unsigned char* Bg = Btile + (size_t)kb * 16384
                                    + wave * 4096 + lane * 16;
            #pragma unroll
            for (int q = 0; q < 4; ++q) {
                __builtin_amdgcn_global_load_lds(
                    (const AS_GLOBAL unsigned int*)(Ag + q * 1024),
                    (AS_LDS unsigned int*)&As[wave * 4096 + q * 1024],
                    16, 0, 0);
                __builtin_amdgcn_global_load_lds(
                    (const AS_GLOBAL unsigned int*)(Bg + q * 1024),
                    (AS_LDS unsigned int*)&Bs[wave * 4096 + q * 1024],
                    16, 0, 0);
            }
        }
        __syncthreads();           // compiler drains vmcnt before barrier

        i32x8 bq[4];
        #pragma unroll
        for (int tj = 0; tj < 4; ++tj) {
            const int ba = bOff0 + tj * 2048;
            union { int4 h[2]; i32x8 v; } u;
            u.h[0] = *(const int4*)&Bs[ba];
            u.h[1] = *(const int4*)&Bs[ba ^ 16];
            bq[tj] = u.v;
        }
        #pragma unroll
        for (int ti = 0; ti < 4; ++ti) {
            const int aa = aOff0 + ti * 2048;
            union { int4 h[2]; i32x8 v; } u;
            u.h[0] = *(const int4*)&As[aa];
            u.h[1] = *(const int4*)&As[aa ^ 16];
            i32x8 af = u.v;
            #pragma unroll
            for (int tj = 0; tj < 4; ++tj)
                acc[ti][tj] = __builtin_amdgcn_mfma_scale_f32_16x16x128_f8f6f4(
                    af, bq[tj], acc[ti][tj],
                    0, 0,          // cbsz=fp8(e4m3), blgp=fp8(e4m3)
                    0, 127,        // scale A: E8M0 127 = x1.0
                    0, 127);       // scale B
        }
        __syncthreads();           // done with LDS before next stage
    }

    const float ls = logit_scale[0];
    const int offs = offset[0];
    const int rowBase = by * 128 + wm * 64;
    const int colBase = bx * 128 + wn * 64;
    #pragma unroll
    for (int ti = 0; ti < 4; ++ti) {
        #pragma unroll
        for (int r = 0; r < 4; ++r) {
            int gi = rowBase + 16 * ti + 4 * qd + r;     // C/D row=quad*4+reg
            float rs = 0.f;
            #pragma unroll
            for (int tj = 0; tj < 4; ++tj) {
                int gj = colBase + 16 * tj + lo;         // C/D col=lane&15
                float e = __expf(ls * acc[ti][tj][r]);
                if (gj == gi + offs) e = 0.f;            // shifted diagonal
                rs += e;
            }
            #pragma unroll
            for (int m = 1; m < 16; m <<= 1) rs += __shfl_xor(rs, m, 64);
            if (lo == 0) atomicAdd(&S[gi], rs);
        }
    }

    // ---- fused final reduction (ticket: last block does it all) ----
    __threadfence();                         // release our S atomics
    if (tid == 0) {
        int t = atomicAdd((int*)&red[2], 1);
        lastFlag = (t == (int)(gridDim.x * gridDim.y * gridDim.z) - 1);
    }
    __syncthreads();
    if (!lastFlag) return;
    __threadfence();                         // acquire all blocks' S writes

    const float inv_rw = 1.0f / (float)(Bn - 1);
    float pg = 0.f, lg = 0.f;
    for (int i = tid; i < Bn; i += 256) {
        float p1 = l1_im[i] / (u_im[i] + EPSF) + l1_tt[i] / (u_tt[i] + EPSF);
        float dd = expf(-ls * diag[i]);
        float p2 = dd * S0[i] * inv_rw / (ru_im[i] + EPSF)
                 + dd * S1[i] * inv_rw / (ru_tt[i] + EPSF);
        pg += p1 + p2;
        lg += logf(u_im[i]) + logf(u_tt[i]);
    }
    float* sp = (float*)As;                  // LDS free after K-loop
    float* sl = sp + 256;
    sp[tid] = pg; sl[tid] = lg;
    __syncthreads();
    for (int s = 128; s > 0; s >>= 1) {
        if (tid < s) { sp[tid] += sp[tid + s]; sl[tid] += sl[tid + s]; }
        __syncthreads();
    }
    if (tid == 0) {
        float loss = ((sp[0] / (float)Bn) * 0.5f) / ls
                   + RHOF / ls
                   + (sl[0] / (float)Bn) * 0.5f / ls;
        out[0] = loss;
    }
}

extern "C" void kernel_launch(void* const* d_in, const int* in_sizes, int n_in,
                              void* d_out, int out_size, void* d_ws, size_t ws_size,
                              hipStream_t stream) {
    const float* im    = (const float*)d_in[0];
    const float* tt    = (const float*)d_in[1];
    const float* rim   = (const float*)d_in[2];
    const float* rtt   = (const float*)d_in[3];
    const float* ru_im = (const float*)d_in[4];
    const float* ru_tt = (const float*)d_in[5];
    const float* l1_im = (const float*)d_in[6];
    const float* l1_tt = (const float*)d_in[7];
    const float* u_im  = (const float*)d_in[8];
    const float* u_tt  = (const float*)d_in[9];
    const float* lsc   = (const float*)d_in[10];
    const int*   offs  = (const int*)d_in[11];

    const int Bn = in_sizes[4];          // 4096
    const int D  = in_sizes[0] / Bn;     // 1024
    const int nComb = Bn / 2;            // rim+rtt combined blocks (2 rows)
    const int bpm = Bn * D / (256 * 16); // im/tt conversion blocks (4 rows)

    char* base = (char*)d_ws;
    float* S_im = (float*)base;
    float* S_tt = S_im + Bn;
    float* diag = S_tt + Bn;
    float* red  = diag + Bn;             // [2]=ticket
    const size_t headBytes = (((size_t)(3 * Bn + 8) * sizeof(float)) + 255) & ~(size_t)255;
    const size_t matBytes  = (size_t)Bn * D;          // fp8: 1 B/elem
    unsigned char* buf0 = (unsigned char*)(base + headBytes);
    unsigned char* bRim = buf0;
    unsigned char* bTt  = buf0 + matBytes;
    unsigned char* bRtt = buf0 + 2 * matBytes;
    unsigned char* bIm  = buf0 + 3 * matBytes;

    prep_fp8<<<nComb + 2 * bpm, 256, 0, stream>>>(
        im, tt, rim, rtt, bIm, bTt, bRim, bRtt, S_im, S_tt, diag, red,
        D, nComb, bpm);

    dim3 ggrid(Bn / 128, Bn / 128, 2);
    gemm_expsum<<<ggrid, 256, 0, stream>>>(
        bRim, bTt, S_im, bRtt, bIm, S_tt, lsc, offs,
        diag, ru_im, ru_tt, l1_im, l1_tt, u_im, u_tt,
        red, (float*)d_out, Bn, D);
}

// Round 12
// 173.577 us; speedup vs baseline: 1.7242x; 1.6442x over previous
//
#include <hip/hip_runtime.h>
#include <hip/hip_bf16.h>

#define EPSF 1e-14f
#define RHOF 8.0f

typedef __attribute__((ext_vector_type(4))) float f32x4;
typedef __attribute__((ext_vector_type(8))) int   i32x8;

#define AS_GLOBAL __attribute__((address_space(1)))
#define AS_LDS    __attribute__((address_space(3)))

// fp8 packed layout, BK=128 (for mfma_scale 16x16x128). Tile = 128 rows x
// 128 cols fp8 = 16 KB = 1024 units of 16 B. Row r = 8 units; content unit
// u stored at slot u ^ (r&7). Fragment (quad qd) needs k-block qd*32..+31 =
// content units {2qd, 2qd+1} -> slots s0=(2qd)^(lo&7), s0^1.
// global_load_lds deposit order == packed order.

// One-pass prep with FUSED diag (r11-verified):
//  - blocks [0, nComb):   rim+rtt combined, 2 rows: convert + diag dot.
//  - blocks [nComb, +bpm): im conversion (4 rows/block).
//  - blocks [+bpm, +2bpm): tt conversion.
__global__ __launch_bounds__(256) void prep_fp8(
    const float* __restrict__ im,  const float* __restrict__ tt,
    const float* __restrict__ rim, const float* __restrict__ rtt,
    unsigned char* __restrict__ bIm,  unsigned char* __restrict__ bTt,
    unsigned char* __restrict__ bRim, unsigned char* __restrict__ bRtt,
    float* __restrict__ S_im, float* __restrict__ S_tt,
    float* __restrict__ diag, float* __restrict__ red,
    int D, int nComb, int bpm)
{
    const int b = blockIdx.x;
    const int tid = threadIdx.x;
    const int kTiles = D >> 7;

    if (b < nComb) {
        __shared__ float4 Lf[2][72][4];          // padded: slot c+(c>>3)
        const int half = tid >> 7;               // 0 = rim, 1 = rtt
        const int t2   = tid & 127;
        const int urow = t2 >> 6;
        const int c    = t2 & 63;                // unit within row (D=1024)
        const int r    = b * 2 + urow;
        const float* src = half ? rtt : rim;
        unsigned char* dst = half ? bRtt : bRim;

        const float* p = src + (size_t)r * D + (size_t)c * 16;
        float4 v0 = ((const float4*)p)[0];
        float4 v1 = ((const float4*)p)[1];
        float4 v2 = ((const float4*)p)[2];
        float4 v3 = ((const float4*)p)[3];
        int w0 = __builtin_amdgcn_cvt_pk_fp8_f32(v0.x, v0.y, 0, false);
        w0     = __builtin_amdgcn_cvt_pk_fp8_f32(v0.z, v0.w, w0, true);
        int w1 = __builtin_amdgcn_cvt_pk_fp8_f32(v1.x, v1.y, 0, false);
        w1     = __builtin_amdgcn_cvt_pk_fp8_f32(v1.z, v1.w, w1, true);
        int w2 = __builtin_amdgcn_cvt_pk_fp8_f32(v2.x, v2.y, 0, false);
        w2     = __builtin_amdgcn_cvt_pk_fp8_f32(v2.z, v2.w, w2, true);
        int w3 = __builtin_amdgcn_cvt_pk_fp8_f32(v3.x, v3.y, 0, false);
        w3     = __builtin_amdgcn_cvt_pk_fp8_f32(v3.z, v3.w, w3, true);
        int4 out = make_int4(w0, w1, w2, w3);
        const int kb = c >> 3;
        const int p8 = (c & 7) ^ (r & 7);        // XOR slot
        *(int4*)(dst + ((size_t)((r >> 7) * kTiles + kb) * 1024
                        + (size_t)(r & 127) * 8 + p8) * 16) = out;

        const int cs = c + (c >> 3);             // padded LDS slot
        if (!half) {
            Lf[urow][cs][0] = v0; Lf[urow][cs][1] = v1;
            Lf[urow][cs][2] = v2; Lf[urow][cs][3] = v3;
        }
        if (tid < 2) { S_im[b * 2 + tid] = 0.f; S_tt[b * 2 + tid] = 0.f; }
        if (b == 0 && tid >= 8 && tid < 16) red[tid - 8] = 0.f;
        __syncthreads();
        if (half) {
            float4 a0 = Lf[urow][cs][0], a1 = Lf[urow][cs][1];
            float4 a2 = Lf[urow][cs][2], a3 = Lf[urow][cs][3];
            float s = a0.x*v0.x + a0.y*v0.y + a0.z*v0.z + a0.w*v0.w
                    + a1.x*v1.x + a1.y*v1.y + a1.z*v1.z + a1.w*v1.w
                    + a2.x*v2.x + a2.y*v2.y + a2.z*v2.z + a2.w*v2.w
                    + a3.x*v3.x + a3.y*v3.y + a3.z*v3.z + a3.w*v3.w;
            #pragma unroll
            for (int m2 = 1; m2 < 64; m2 <<= 1) s += __shfl_xor(s, m2, 64);
            if (c == 0) diag[r] = s;
        }
    } else {
        int b2 = b - nComb;
        const int isTT = (b2 >= bpm);
        const int blk  = isTT ? b2 - bpm : b2;
        const float* src = isTT ? tt : im;
        unsigned char* dst = isTT ? bTt : bIm;
        const int upr = D >> 4;                  // 64 units per row
        const int urow = tid / upr;
        const int c    = tid - urow * upr;
        const int r    = blk * (256 / upr) + urow;
        const float* p = src + (size_t)r * D + (size_t)c * 16;
        float4 v0 = ((const float4*)p)[0];
        float4 v1 = ((const float4*)p)[1];
        float4 v2 = ((const float4*)p)[2];
        float4 v3 = ((const float4*)p)[3];
        int w0 = __builtin_amdgcn_cvt_pk_fp8_f32(v0.x, v0.y, 0, false);
        w0     = __builtin_amdgcn_cvt_pk_fp8_f32(v0.z, v0.w, w0, true);
        int w1 = __builtin_amdgcn_cvt_pk_fp8_f32(v1.x, v1.y, 0, false);
        w1     = __builtin_amdgcn_cvt_pk_fp8_f32(v1.z, v1.w, w1, true);
        int w2 = __builtin_amdgcn_cvt_pk_fp8_f32(v2.x, v2.y, 0, false);
        w2     = __builtin_amdgcn_cvt_pk_fp8_f32(v2.z, v2.w, w2, true);
        int w3 = __builtin_amdgcn_cvt_pk_fp8_f32(v3.x, v3.y, 0, false);
        w3     = __builtin_amdgcn_cvt_pk_fp8_f32(v3.z, v3.w, w3, true);
        int4 out = make_int4(w0, w1, w2, w3);
        const int kb = c >> 3;
        const int p8 = (c & 7) ^ (r & 7);
        *(int4*)(dst + ((size_t)((r >> 7) * kTiles + kb) * 1024
                        + (size_t)(r & 127) * 8 + p8) * 16) = out;
    }
}

// MX-scaled fp8 GEMM, 256x256 tile, 8 waves (2M x 4N), BK=128, dbuf LDS.
// z-merged: 256 fat blocks (1/CU); free-running compiler-scheduled K-loop
// (r5 structure, best measured 60.3 us). Boundary = per-wave vmcnt(0) on
// own DMA issued a full tile ago + raw s_barrier.
// FUSED final reduction with CHEAP release: per-wave s_waitcnt vmcnt(0)
// (atomic-no-return retires when performed at coherence point) +
// __syncthreads() (all waves' atomics done) -> ticket. The expensive
// __threadfence() (L2 writeback/invalidate) runs ONLY in the last block
// -- r10/r11's 3x regression was 2048 per-block threadfences.
__global__ __launch_bounds__(512, 2) void gemm_expsum(
    const unsigned char* __restrict__ A0, const unsigned char* __restrict__ B0,
    float* __restrict__ S0,
    const unsigned char* __restrict__ A1, const unsigned char* __restrict__ B1,
    float* __restrict__ S1,
    const float* __restrict__ logit_scale, const int* __restrict__ offset,
    const float* __restrict__ diag,
    const float* __restrict__ ru_im, const float* __restrict__ ru_tt,
    const float* __restrict__ l1_im, const float* __restrict__ l1_tt,
    const float* __restrict__ u_im,  const float* __restrict__ u_tt,
    float* __restrict__ red, float* __restrict__ out,
    int Bn, int D)
{
    __shared__ unsigned char As[2][32768];   // 2 x (128-row halves), dbuf
    __shared__ unsigned char Bs[2][32768];
    __shared__ int lastFlag;

    const int tid  = threadIdx.x;
    const int wave = tid >> 6;
    const int lane = tid & 63;
    const int lo   = lane & 15;
    const int qd   = lane >> 4;
    const int wm   = wave >> 2;              // 0..1  (M half)
    const int wn   = wave & 3;               // 0..3  (N quarter)
    const int offA = ((2 * qd) ^ (lo & 7)) * 16;   // first 16-B slot

    // XCD-bijective swizzle (nwg = 256, % 8 == 0).
    const int nx  = gridDim.x;
    const int nwg = nx * gridDim.y;
    int wg = blockIdx.y * nx + blockIdx.x;
    int swz = ((nwg & 7) == 0) ? ((wg & 7) * (nwg >> 3) + (wg >> 3)) : wg;
    const int by = swz / nx;
    const int bx = swz - by * nx;

    const int kTiles = D >> 7;

    // Owner staging: wave pair (wave>>1) owns one 16 KB half-tile
    // {A-h0,A-h1,B-h0,B-h1}; part = wave&1 stages 8 KB (8 x 16 B / lane).
    const int half = wave >> 1;
    const int part = wave & 1;
    const bool ownerIsA = (half < 2);
    const int ownerLoff = (half & 1) * 16384 + part * 8192;

    auto stageOwner = [&](int buf, const unsigned char* At,
                          const unsigned char* Bt, int kb) {
        const unsigned char* g =
            (ownerIsA ? At + (size_t)half * kTiles * 16384
                      : Bt + (size_t)(half - 2) * kTiles * 16384)
            + (size_t)kb * 16384 + part * 8192 + lane * 16;
        unsigned char* l = (ownerIsA ? &As[buf][0] : &Bs[buf][0]) + ownerLoff;
        #pragma unroll
        for (int q = 0; q < 8; ++q)
            __builtin_amdgcn_global_load_lds(
                (const AS_GLOBAL unsigned int*)(g + q * 1024),
                (AS_LDS unsigned int*)(l + q * 1024), 16, 0, 0);
    };

    // per-lane LDS fragment bases (r&7 == lo&7 for all ti/tj)
    const int aOff0 = wm * 16384 + lo * 128 + offA;                 // + ti*2048
    const int bOff0 = (wn >> 1) * 16384 + ((wn & 1) * 64 + lo) * 128 + offA;

    const float ls = logit_scale[0];
    const int offs = offset[0];

    for (int zz = 0; zz < 2; ++zz) {
        const unsigned char* A = zz ? A1 : A0;
        const unsigned char* B = zz ? B1 : B0;
        float* S = zz ? S1 : S0;
        const unsigned char* Atile = A + (size_t)(2 * by) * kTiles * 16384;
        const unsigned char* Btile = B + (size_t)(2 * bx) * kTiles * 16384;

        f32x4 acc[8][4];
        #pragma unroll
        for (int i = 0; i < 8; ++i)
            #pragma unroll
            for (int j = 0; j < 4; ++j)
                acc[i][j] = (f32x4){0.f, 0.f, 0.f, 0.f};

        if (zz == 0) {                       // cold prologue (z0 only)
            stageOwner(0, Atile, Btile, 0);
            asm volatile("s_waitcnt vmcnt(0)" ::: "memory");
            __builtin_amdgcn_s_barrier();
        }
        // zz==1: tile0 staged at z0's last K-tile, drained under z0's
        // epilogue; sits in buf0 (kTiles even -> parity matches).

        for (int kb = 0; kb < kTiles; ++kb) {
            const int cur = kb & 1;
            if (kb + 1 < kTiles) {
                stageOwner(1 - cur, Atile, Btile, kb + 1);
            } else if (zz == 0) {            // last z0 tile: stage z1 tile0
                stageOwner(1 - cur,
                           A1 + (size_t)(2 * by) * kTiles * 16384,
                           B1 + (size_t)(2 * bx) * kTiles * 16384, 0);
            }

            i32x8 bq[4];
            #pragma unroll
            for (int tj = 0; tj < 4; ++tj) {
                const int ba = bOff0 + tj * 2048;
                union { int4 h[2]; i32x8 v; } u;
                u.h[0] = *(const int4*)&Bs[cur][ba];
                u.h[1] = *(const int4*)&Bs[cur][ba ^ 16];
                bq[tj] = u.v;
            }

            // One scheduler region: 16 ds_read_b128 + 32 MFMA; compiler
            // interleaves with fine lgkmcnt, waves drift -> LDS || MFMA.
            #pragma unroll
            for (int ph = 0; ph < 4; ++ph) {
                const int ti0 = 2 * ph;
                union { int4 h[2]; i32x8 v; } ua0, ua1;
                {
                    const int aa0 = aOff0 + ti0 * 2048;
                    ua0.h[0] = *(const int4*)&As[cur][aa0];
                    ua0.h[1] = *(const int4*)&As[cur][aa0 ^ 16];
                    const int aa1 = aOff0 + (ti0 + 1) * 2048;
                    ua1.h[0] = *(const int4*)&As[cur][aa1];
                    ua1.h[1] = *(const int4*)&As[cur][aa1 ^ 16];
                }
                #pragma unroll
                for (int tj = 0; tj < 4; ++tj)
                    acc[ti0][tj] = __builtin_amdgcn_mfma_scale_f32_16x16x128_f8f6f4(
                        ua0.v, bq[tj], acc[ti0][tj],
                        0, 0, 0, 127, 0, 127);
                #pragma unroll
                for (int tj = 0; tj < 4; ++tj)
                    acc[ti0 + 1][tj] = __builtin_amdgcn_mfma_scale_f32_16x16x128_f8f6f4(
                        ua1.v, bq[tj], acc[ti0 + 1][tj],
                        0, 0, 0, 127, 0, 127);
            }

            if (kb + 1 < kTiles) {
                // own DMA for kb+1 issued a full tile ago: cheap drain
                asm volatile("s_waitcnt vmcnt(0)" ::: "memory");
                __builtin_amdgcn_s_barrier();
            }
        }

        // epilogue for this z; z1's tile-0 DMA (if zz==0) flies under it
        const int rowBase = by * 256 + wm * 128;
        const int colBase = bx * 256 + wn * 64;
        #pragma unroll
        for (int ti = 0; ti < 8; ++ti) {
            #pragma unroll
            for (int r = 0; r < 4; ++r) {
                int gi = rowBase + 16 * ti + 4 * qd + r; // C/D row=quad*4+reg
                float rs = 0.f;
                #pragma unroll
                for (int tj = 0; tj < 4; ++tj) {
                    int gj = colBase + 16 * tj + lo;     // C/D col=lane&15
                    float e = __expf(ls * acc[ti][tj][r]);
                    if (gj == gi + offs) e = 0.f;        // shifted diagonal
                    rs += e;
                }
                #pragma unroll
                for (int m = 1; m < 16; m <<= 1) rs += __shfl_xor(rs, m, 64);
                if (lo == 0) atomicAdd(&S[gi], rs);
            }
        }

        if (zz == 0) {                       // drain z1 tile0 before z1 loop
            asm volatile("s_waitcnt vmcnt(0)" ::: "memory");
            __builtin_amdgcn_s_barrier();
        }
    }

    // ---- fused final reduction (cheap release, single acquire) ----
    asm volatile("s_waitcnt vmcnt(0)" ::: "memory");  // own S atomics done
    __syncthreads();                     // all waves' atomics performed
    if (tid == 0) {
        int t = atomicAdd((int*)&red[2], 1);
        lastFlag = (t == nwg - 1);
    }
    __syncthreads();
    if (!lastFlag) return;
    __threadfence();                     // acquire (one block only)

    const float inv_rw = 1.0f / (float)(Bn - 1);
    float pg = 0.f, lg = 0.f;
    for (int i = tid; i < Bn; i += 512) {
        float p1 = l1_im[i] / (u_im[i] + EPSF) + l1_tt[i] / (u_tt[i] + EPSF);
        float dd = expf(-ls * diag[i]);
        float p2 = dd * S0[i] * inv_rw / (ru_im[i] + EPSF)
                 + dd * S1[i] * inv_rw / (ru_tt[i] + EPSF);
        pg += p1 + p2;
        lg += logf(u_im[i]) + logf(u_tt[i]);
    }
    float* sp = (float*)&As[0][0];       // LDS free after K-loop
    float* sl = sp + 512;
    sp[tid] = pg; sl[tid] = lg;
    __syncthreads();
    for (int s = 256; s > 0; s >>= 1) {
        if (tid < s) { sp[tid] += sp[tid + s]; sl[tid] += sl[tid + s]; }
        __syncthreads();
    }
    if (tid == 0) {
        float loss = ((sp[0] / (float)Bn) * 0.5f) / ls
                   + RHOF / ls
                   + (sl[0] / (float)Bn) * 0.5f / ls;
        out[0] = loss;
    }
}

extern "C" void kernel_launch(void* const* d_in, const int* in_sizes, int n_in,
                              void* d_out, int out_size, void* d_ws, size_t ws_size,
                              hipStream_t stream) {
    const float* im    = (const float*)d_in[0];
    const float* tt    = (const float*)d_in[1];
    const float* rim   = (const float*)d_in[2];
    const float* rtt   = (const float*)d_in[3];
    const float* ru_im = (const float*)d_in[4];
    const float* ru_tt = (const float*)d_in[5];
    const float* l1_im = (const float*)d_in[6];
    const float* l1_tt = (const float*)d_in[7];
    const float* u_im  = (const float*)d_in[8];
    const float* u_tt  = (const float*)d_in[9];
    const float* lsc   = (const float*)d_in[10];
    const int*   offs  = (const int*)d_in[11];

    const int Bn = in_sizes[4];          // 4096
    const int D  = in_sizes[0] / Bn;     // 1024
    const int nComb = Bn / 2;            // rim+rtt combined blocks (2 rows)
    const int bpm = Bn * D / (256 * 16); // im/tt conversion blocks (4 rows)

    char* base = (char*)d_ws;
    float* S_im = (float*)base;
    float* S_tt = S_im + Bn;
    float* diag = S_tt + Bn;
    float* red  = diag + Bn;             // [2]=ticket
    const size_t headBytes = (((size_t)(3 * Bn + 8) * sizeof(float)) + 255) & ~(size_t)255;
    const size_t matBytes  = (size_t)Bn * D;          // fp8: 1 B/elem
    unsigned char* buf0 = (unsigned char*)(base + headBytes);
    unsigned char* bRim = buf0;
    unsigned char* bTt  = buf0 + matBytes;
    unsigned char* bRtt = buf0 + 2 * matBytes;
    unsigned char* bIm  = buf0 + 3 * matBytes;

    prep_fp8<<<nComb + 2 * bpm, 256, 0, stream>>>(
        im, tt, rim, rtt, bIm, bTt, bRim, bRtt, S_im, S_tt, diag, red,
        D, nComb, bpm);

    dim3 ggrid(Bn / 256, Bn / 256, 1);
    gemm_expsum<<<ggrid, 512, 0, stream>>>(
        bRim, bTt, S_im, bRtt, bIm, S_tt, lsc, offs,
        diag, ru_im, ru_tt, l1_im, l1_tt, u_im, u_tt,
        red, (float*)d_out, Bn, D);
}

// Round 13
// 172.170 us; speedup vs baseline: 1.7383x; 1.0082x over previous
//
#include <hip/hip_runtime.h>
#include <hip/hip_bf16.h>

#define EPSF 1e-14f
#define RHOF 8.0f

typedef __attribute__((ext_vector_type(4))) float f32x4;
typedef __attribute__((ext_vector_type(8))) int   i32x8;

#define AS_GLOBAL __attribute__((address_space(1)))
#define AS_LDS    __attribute__((address_space(3)))

// fp8 packed layout, BK=128 (for mfma_scale 16x16x128). Tile = 128 rows x
// 128 cols fp8 = 16 KB = 1024 units of 16 B. Row r = 8 units; content unit
// u stored at slot u ^ (r&7). Fragment (quad qd) needs k-block qd*32..+31 =
// content units {2qd, 2qd+1} -> slots s0=(2qd)^(lo&7), s0^1.
// global_load_lds deposit order == packed order.

// One-pass prep with FUSED diag AND the S-independent loss terms:
//  - blocks [0, nComb): rim+rtt combined, 2 rows: convert + diag dot ->
//    per-row coef_im/coef_tt (= e^{-ls*diag}*inv_rw/(ru+eps)), p1arr, lgarr.
//    All cold input reads (ru/l1/u) + logf/expf happen HERE, hidden under
//    4096 parallel blocks -- not in the gemm's serial last-block tail (the
//    r12 +10us regression).
//  - blocks [nComb, +bpm): im conversion.  [+bpm, +2bpm): tt conversion.
__global__ __launch_bounds__(256) void prep_fp8(
    const float* __restrict__ im,  const float* __restrict__ tt,
    const float* __restrict__ rim, const float* __restrict__ rtt,
    unsigned char* __restrict__ bIm,  unsigned char* __restrict__ bTt,
    unsigned char* __restrict__ bRim, unsigned char* __restrict__ bRtt,
    float* __restrict__ S_im, float* __restrict__ S_tt,
    float* __restrict__ coef_im, float* __restrict__ coef_tt,
    float* __restrict__ p1arr, float* __restrict__ lgarr,
    float* __restrict__ red,
    const float* __restrict__ logit_scale,
    const float* __restrict__ ru_im, const float* __restrict__ ru_tt,
    const float* __restrict__ l1_im, const float* __restrict__ l1_tt,
    const float* __restrict__ u_im,  const float* __restrict__ u_tt,
    int D, int nComb, int bpm, int Bn)
{
    const int b = blockIdx.x;
    const int tid = threadIdx.x;
    const int kTiles = D >> 7;

    if (b < nComb) {
        __shared__ float4 Lf[2][72][4];          // padded: slot c+(c>>3)
        const int half = tid >> 7;               // 0 = rim, 1 = rtt
        const int t2   = tid & 127;
        const int urow = t2 >> 6;
        const int c    = t2 & 63;                // unit within row (D=1024)
        const int r    = b * 2 + urow;
        const float* src = half ? rtt : rim;
        unsigned char* dst = half ? bRtt : bRim;

        const float* p = src + (size_t)r * D + (size_t)c * 16;
        float4 v0 = ((const float4*)p)[0];
        float4 v1 = ((const float4*)p)[1];
        float4 v2 = ((const float4*)p)[2];
        float4 v3 = ((const float4*)p)[3];
        int w0 = __builtin_amdgcn_cvt_pk_fp8_f32(v0.x, v0.y, 0, false);
        w0     = __builtin_amdgcn_cvt_pk_fp8_f32(v0.z, v0.w, w0, true);
        int w1 = __builtin_amdgcn_cvt_pk_fp8_f32(v1.x, v1.y, 0, false);
        w1     = __builtin_amdgcn_cvt_pk_fp8_f32(v1.z, v1.w, w1, true);
        int w2 = __builtin_amdgcn_cvt_pk_fp8_f32(v2.x, v2.y, 0, false);
        w2     = __builtin_amdgcn_cvt_pk_fp8_f32(v2.z, v2.w, w2, true);
        int w3 = __builtin_amdgcn_cvt_pk_fp8_f32(v3.x, v3.y, 0, false);
        w3     = __builtin_amdgcn_cvt_pk_fp8_f32(v3.z, v3.w, w3, true);
        int4 out = make_int4(w0, w1, w2, w3);
        const int kb = c >> 3;
        const int p8 = (c & 7) ^ (r & 7);        // XOR slot
        *(int4*)(dst + ((size_t)((r >> 7) * kTiles + kb) * 1024
                        + (size_t)(r & 127) * 8 + p8) * 16) = out;

        const int cs = c + (c >> 3);             // padded LDS slot
        if (!half) {
            Lf[urow][cs][0] = v0; Lf[urow][cs][1] = v1;
            Lf[urow][cs][2] = v2; Lf[urow][cs][3] = v3;
        }
        if (tid < 2) { S_im[b * 2 + tid] = 0.f; S_tt[b * 2 + tid] = 0.f; }
        if (b == 0 && tid == 0) red[2] = 0.f;    // ticket reset (pre-gemm)
        __syncthreads();
        if (half) {
            float4 a0 = Lf[urow][cs][0], a1 = Lf[urow][cs][1];
            float4 a2 = Lf[urow][cs][2], a3 = Lf[urow][cs][3];
            float s = a0.x*v0.x + a0.y*v0.y + a0.z*v0.z + a0.w*v0.w
                    + a1.x*v1.x + a1.y*v1.y + a1.z*v1.z + a1.w*v1.w
                    + a2.x*v2.x + a2.y*v2.y + a2.z*v2.z + a2.w*v2.w
                    + a3.x*v3.x + a3.y*v3.y + a3.z*v3.z + a3.w*v3.w;
            #pragma unroll
            for (int m2 = 1; m2 < 64; m2 <<= 1) s += __shfl_xor(s, m2, 64);
            if (c == 0) {                        // one lane per row
                const float ls = logit_scale[0];
                const float inv_rw = 1.0f / (float)(Bn - 1);
                float dd = expf(-ls * s);
                coef_im[r] = dd * inv_rw / (ru_im[r] + EPSF);
                coef_tt[r] = dd * inv_rw / (ru_tt[r] + EPSF);
                p1arr[r] = l1_im[r] / (u_im[r] + EPSF)
                         + l1_tt[r] / (u_tt[r] + EPSF);
                lgarr[r] = logf(u_im[r]) + logf(u_tt[r]);
            }
        }
    } else {
        int b2 = b - nComb;
        const int isTT = (b2 >= bpm);
        const int blk  = isTT ? b2 - bpm : b2;
        const float* src = isTT ? tt : im;
        unsigned char* dst = isTT ? bTt : bIm;
        const int upr = D >> 4;                  // 64 units per row
        const int urow = tid / upr;
        const int c    = tid - urow * upr;
        const int r    = blk * (256 / upr) + urow;
        const float* p = src + (size_t)r * D + (size_t)c * 16;
        float4 v0 = ((const float4*)p)[0];
        float4 v1 = ((const float4*)p)[1];
        float4 v2 = ((const float4*)p)[2];
        float4 v3 = ((const float4*)p)[3];
        int w0 = __builtin_amdgcn_cvt_pk_fp8_f32(v0.x, v0.y, 0, false);
        w0     = __builtin_amdgcn_cvt_pk_fp8_f32(v0.z, v0.w, w0, true);
        int w1 = __builtin_amdgcn_cvt_pk_fp8_f32(v1.x, v1.y, 0, false);
        w1     = __builtin_amdgcn_cvt_pk_fp8_f32(v1.z, v1.w, w1, true);
        int w2 = __builtin_amdgcn_cvt_pk_fp8_f32(v2.x, v2.y, 0, false);
        w2     = __builtin_amdgcn_cvt_pk_fp8_f32(v2.z, v2.w, w2, true);
        int w3 = __builtin_amdgcn_cvt_pk_fp8_f32(v3.x, v3.y, 0, false);
        w3     = __builtin_amdgcn_cvt_pk_fp8_f32(v3.z, v3.w, w3, true);
        int4 out = make_int4(w0, w1, w2, w3);
        const int kb = c >> 3;
        const int p8 = (c & 7) ^ (r & 7);
        *(int4*)(dst + ((size_t)((r >> 7) * kTiles + kb) * 1024
                        + (size_t)(r & 127) * 8 + p8) * 16) = out;
    }
}

// MX-scaled fp8 GEMM, 256x256 tile, 8 waves (2M x 4N), BK=128, dbuf LDS.
// z-merged: 256 fat blocks (1/CU); free-running compiler-scheduled K-loop
// (r5 structure). Boundary = per-wave vmcnt(0) on own DMA issued a full
// tile ago + raw s_barrier.
// FUSED final reduction, SLIM tail: last block reduces only the S-dependent
// terms against prep-precomputed L2-hot coef/p1/lg arrays (~96 KB L2) --
// r12's 160 KB cold-HBM + logf serial tail cost +10us per dispatch.
__global__ __launch_bounds__(512, 2) void gemm_expsum(
    const unsigned char* __restrict__ A0, const unsigned char* __restrict__ B0,
    float* __restrict__ S0,
    const unsigned char* __restrict__ A1, const unsigned char* __restrict__ B1,
    float* __restrict__ S1,
    const float* __restrict__ logit_scale, const int* __restrict__ offset,
    const float* __restrict__ coef_im, const float* __restrict__ coef_tt,
    const float* __restrict__ p1arr, const float* __restrict__ lgarr,
    float* __restrict__ red, float* __restrict__ out,
    int Bn, int D)
{
    __shared__ unsigned char As[2][32768];   // 2 x (128-row halves), dbuf
    __shared__ unsigned char Bs[2][32768];
    __shared__ int lastFlag;

    const int tid  = threadIdx.x;
    const int wave = tid >> 6;
    const int lane = tid & 63;
    const int lo   = lane & 15;
    const int qd   = lane >> 4;
    const int wm   = wave >> 2;              // 0..1  (M half)
    const int wn   = wave & 3;               // 0..3  (N quarter)
    const int offA = ((2 * qd) ^ (lo & 7)) * 16;   // first 16-B slot

    // XCD-bijective swizzle (nwg = 256, % 8 == 0).
    const int nx  = gridDim.x;
    const int nwg = nx * gridDim.y;
    int wg = blockIdx.y * nx + blockIdx.x;
    int swz = ((nwg & 7) == 0) ? ((wg & 7) * (nwg >> 3) + (wg >> 3)) : wg;
    const int by = swz / nx;
    const int bx = swz - by * nx;

    const int kTiles = D >> 7;

    // Owner staging: wave pair (wave>>1) owns one 16 KB half-tile
    // {A-h0,A-h1,B-h0,B-h1}; part = wave&1 stages 8 KB (8 x 16 B / lane).
    const int half = wave >> 1;
    const int part = wave & 1;
    const bool ownerIsA = (half < 2);
    const int ownerLoff = (half & 1) * 16384 + part * 8192;

    auto stageOwner = [&](int buf, const unsigned char* At,
                          const unsigned char* Bt, int kb) {
        const unsigned char* g =
            (ownerIsA ? At + (size_t)half * kTiles * 16384
                      : Bt + (size_t)(half - 2) * kTiles * 16384)
            + (size_t)kb * 16384 + part * 8192 + lane * 16;
        unsigned char* l = (ownerIsA ? &As[buf][0] : &Bs[buf][0]) + ownerLoff;
        #pragma unroll
        for (int q = 0; q < 8; ++q)
            __builtin_amdgcn_global_load_lds(
                (const AS_GLOBAL unsigned int*)(g + q * 1024),
                (AS_LDS unsigned int*)(l + q * 1024), 16, 0, 0);
    };

    // per-lane LDS fragment bases (r&7 == lo&7 for all ti/tj)
    const int aOff0 = wm * 16384 + lo * 128 + offA;                 // + ti*2048
    const int bOff0 = (wn >> 1) * 16384 + ((wn & 1) * 64 + lo) * 128 + offA;

    const float ls = logit_scale[0];
    const int offs = offset[0];

    for (int zz = 0; zz < 2; ++zz) {
        const unsigned char* A = zz ? A1 : A0;
        const unsigned char* B = zz ? B1 : B0;
        float* S = zz ? S1 : S0;
        const unsigned char* Atile = A + (size_t)(2 * by) * kTiles * 16384;
        const unsigned char* Btile = B + (size_t)(2 * bx) * kTiles * 16384;

        f32x4 acc[8][4];
        #pragma unroll
        for (int i = 0; i < 8; ++i)
            #pragma unroll
            for (int j = 0; j < 4; ++j)
                acc[i][j] = (f32x4){0.f, 0.f, 0.f, 0.f};

        if (zz == 0) {                       // cold prologue (z0 only)
            stageOwner(0, Atile, Btile, 0);
            asm volatile("s_waitcnt vmcnt(0)" ::: "memory");
            __builtin_amdgcn_s_barrier();
        }
        // zz==1: tile0 staged at z0's last K-tile, drained under z0's
        // epilogue; sits in buf0 (kTiles even -> parity matches).

        for (int kb = 0; kb < kTiles; ++kb) {
            const int cur = kb & 1;
            if (kb + 1 < kTiles) {
                stageOwner(1 - cur, Atile, Btile, kb + 1);
            } else if (zz == 0) {            // last z0 tile: stage z1 tile0
                stageOwner(1 - cur,
                           A1 + (size_t)(2 * by) * kTiles * 16384,
                           B1 + (size_t)(2 * bx) * kTiles * 16384, 0);
            }

            i32x8 bq[4];
            #pragma unroll
            for (int tj = 0; tj < 4; ++tj) {
                const int ba = bOff0 + tj * 2048;
                union { int4 h[2]; i32x8 v; } u;
                u.h[0] = *(const int4*)&Bs[cur][ba];
                u.h[1] = *(const int4*)&Bs[cur][ba ^ 16];
                bq[tj] = u.v;
            }

            // One scheduler region: 16 ds_read_b128 + 32 MFMA; compiler
            // interleaves with fine lgkmcnt, waves drift -> LDS || MFMA.
            #pragma unroll
            for (int ph = 0; ph < 4; ++ph) {
                const int ti0 = 2 * ph;
                union { int4 h[2]; i32x8 v; } ua0, ua1;
                {
                    const int aa0 = aOff0 + ti0 * 2048;
                    ua0.h[0] = *(const int4*)&As[cur][aa0];
                    ua0.h[1] = *(const int4*)&As[cur][aa0 ^ 16];
                    const int aa1 = aOff0 + (ti0 + 1) * 2048;
                    ua1.h[0] = *(const int4*)&As[cur][aa1];
                    ua1.h[1] = *(const int4*)&As[cur][aa1 ^ 16];
                }
                #pragma unroll
                for (int tj = 0; tj < 4; ++tj)
                    acc[ti0][tj] = __builtin_amdgcn_mfma_scale_f32_16x16x128_f8f6f4(
                        ua0.v, bq[tj], acc[ti0][tj],
                        0, 0, 0, 127, 0, 127);
                #pragma unroll
                for (int tj = 0; tj < 4; ++tj)
                    acc[ti0 + 1][tj] = __builtin_amdgcn_mfma_scale_f32_16x16x128_f8f6f4(
                        ua1.v, bq[tj], acc[ti0 + 1][tj],
                        0, 0, 0, 127, 0, 127);
            }

            if (kb + 1 < kTiles) {
                // own DMA for kb+1 issued a full tile ago: cheap drain
                asm volatile("s_waitcnt vmcnt(0)" ::: "memory");
                __builtin_amdgcn_s_barrier();
            }
        }

        // epilogue for this z; z1's tile-0 DMA (if zz==0) flies under it
        const int rowBase = by * 256 + wm * 128;
        const int colBase = bx * 256 + wn * 64;
        #pragma unroll
        for (int ti = 0; ti < 8; ++ti) {
            #pragma unroll
            for (int r = 0; r < 4; ++r) {
                int gi = rowBase + 16 * ti + 4 * qd + r; // C/D row=quad*4+reg
                float rs = 0.f;
                #pragma unroll
                for (int tj = 0; tj < 4; ++tj) {
                    int gj = colBase + 16 * tj + lo;     // C/D col=lane&15
                    float e = __expf(ls * acc[ti][tj][r]);
                    if (gj == gi + offs) e = 0.f;        // shifted diagonal
                    rs += e;
                }
                #pragma unroll
                for (int m = 1; m < 16; m <<= 1) rs += __shfl_xor(rs, m, 64);
                if (lo == 0) atomicAdd(&S[gi], rs);
            }
        }

        if (zz == 0) {                       // drain z1 tile0 before z1 loop
            asm volatile("s_waitcnt vmcnt(0)" ::: "memory");
            __builtin_amdgcn_s_barrier();
        }
    }

    // ---- fused final reduction (cheap release; slim L2-hot tail) ----
    asm volatile("s_waitcnt vmcnt(0)" ::: "memory");  // own S atomics done
    __syncthreads();                     // all waves' atomics performed
    if (tid == 0) {
        int t = atomicAdd((int*)&red[2], 1);
        lastFlag = (t == nwg - 1);
    }
    __syncthreads();
    if (!lastFlag) return;
    __threadfence();                     // acquire (one block only)

    float pg = 0.f, lg = 0.f;
    for (int i = tid; i < Bn; i += 512) {
        pg += p1arr[i] + S0[i] * coef_im[i] + S1[i] * coef_tt[i];
        lg += lgarr[i];
    }
    float* sp = (float*)&As[0][0];       // LDS free after K-loop
    float* sl = sp + 512;
    sp[tid] = pg; sl[tid] = lg;
    __syncthreads();
    for (int s = 256; s > 0; s >>= 1) {
        if (tid < s) { sp[tid] += sp[tid + s]; sl[tid] += sl[tid + s]; }
        __syncthreads();
    }
    if (tid == 0) {
        float loss = ((sp[0] / (float)Bn) * 0.5f) / ls
                   + RHOF / ls
                   + (sl[0] / (float)Bn) * 0.5f / ls;
        out[0] = loss;
    }
}

extern "C" void kernel_launch(void* const* d_in, const int* in_sizes, int n_in,
                              void* d_out, int out_size, void* d_ws, size_t ws_size,
                              hipStream_t stream) {
    const float* im    = (const float*)d_in[0];
    const float* tt    = (const float*)d_in[1];
    const float* rim   = (const float*)d_in[2];
    const float* rtt   = (const float*)d_in[3];
    const float* ru_im = (const float*)d_in[4];
    const float* ru_tt = (const float*)d_in[5];
    const float* l1_im = (const float*)d_in[6];
    const float* l1_tt = (const float*)d_in[7];
    const float* u_im  = (const float*)d_in[8];
    const float* u_tt  = (const float*)d_in[9];
    const float* lsc   = (const float*)d_in[10];
    const int*   offs  = (const int*)d_in[11];

    const int Bn = in_sizes[4];          // 4096
    const int D  = in_sizes[0] / Bn;     // 1024
    const int nComb = Bn / 2;            // rim+rtt combined blocks (2 rows)
    const int bpm = Bn * D / (256 * 16); // im/tt conversion blocks (4 rows)

    char* base = (char*)d_ws;
    float* S_im    = (float*)base;
    float* S_tt    = S_im + Bn;
    float* coef_im = S_tt + Bn;
    float* coef_tt = coef_im + Bn;
    float* p1arr   = coef_tt + Bn;
    float* lgarr   = p1arr + Bn;
    float* red     = lgarr + Bn;         // [2]=ticket
    const size_t headBytes = (((size_t)(6 * Bn + 8) * sizeof(float)) + 255) & ~(size_t)255;
    const size_t matBytes  = (size_t)Bn * D;          // fp8: 1 B/elem
    unsigned char* buf0 = (unsigned char*)(base + headBytes);
    unsigned char* bRim = buf0;
    unsigned char* bTt  = buf0 + matBytes;
    unsigned char* bRtt = buf0 + 2 * matBytes;
    unsigned char* bIm  = buf0 + 3 * matBytes;

    prep_fp8<<<nComb + 2 * bpm, 256, 0, stream>>>(
        im, tt, rim, rtt, bIm, bTt, bRim, bRtt,
        S_im, S_tt, coef_im, coef_tt, p1arr, lgarr, red,
        lsc, ru_im, ru_tt, l1_im, l1_tt, u_im, u_tt,
        D, nComb, bpm, Bn);

    dim3 ggrid(Bn / 256, Bn / 256, 1);
    gemm_expsum<<<ggrid, 512, 0, stream>>>(
        bRim, bTt, S_im, bRtt, bIm, S_tt, lsc, offs,
        coef_im, coef_tt, p1arr, lgarr,
        red, (float*)d_out, Bn, D);
}

// Round 14
// 172.048 us; speedup vs baseline: 1.7395x; 1.0007x over previous
//
#include <hip/hip_runtime.h>
#include <hip/hip_bf16.h>

#define EPSF 1e-14f
#define RHOF 8.0f

typedef __attribute__((ext_vector_type(4))) float f32x4;
typedef __attribute__((ext_vector_type(8))) int   i32x8;

#define AS_GLOBAL __attribute__((address_space(1)))
#define AS_LDS    __attribute__((address_space(3)))

// fp8 packed layout, BK=128 (for mfma_scale 16x16x128). Tile = 128 rows x
// 128 cols fp8 = 16 KB = 1024 units of 16 B. Row r = 8 units; content unit
// u stored at slot u ^ (r&7). Fragment (quad qd) needs k-block qd*32..+31 =
// content units {2qd, 2qd+1} -> slots s0=(2qd)^(lo&7), s0^1.
// global_load_lds deposit order == packed order.

// One-pass prep with FUSED diag AND the S-independent loss terms (r13).
__global__ __launch_bounds__(256) void prep_fp8(
    const float* __restrict__ im,  const float* __restrict__ tt,
    const float* __restrict__ rim, const float* __restrict__ rtt,
    unsigned char* __restrict__ bIm,  unsigned char* __restrict__ bTt,
    unsigned char* __restrict__ bRim, unsigned char* __restrict__ bRtt,
    float* __restrict__ S_im, float* __restrict__ S_tt,
    float* __restrict__ coef_im, float* __restrict__ coef_tt,
    float* __restrict__ p1arr, float* __restrict__ lgarr,
    float* __restrict__ red,
    const float* __restrict__ logit_scale,
    const float* __restrict__ ru_im, const float* __restrict__ ru_tt,
    const float* __restrict__ l1_im, const float* __restrict__ l1_tt,
    const float* __restrict__ u_im,  const float* __restrict__ u_tt,
    int D, int nComb, int bpm, int Bn)
{
    const int b = blockIdx.x;
    const int tid = threadIdx.x;
    const int kTiles = D >> 7;

    if (b < nComb) {
        __shared__ float4 Lf[2][72][4];          // padded: slot c+(c>>3)
        const int half = tid >> 7;               // 0 = rim, 1 = rtt
        const int t2   = tid & 127;
        const int urow = t2 >> 6;
        const int c    = t2 & 63;                // unit within row (D=1024)
        const int r    = b * 2 + urow;
        const float* src = half ? rtt : rim;
        unsigned char* dst = half ? bRtt : bRim;

        const float* p = src + (size_t)r * D + (size_t)c * 16;
        float4 v0 = ((const float4*)p)[0];
        float4 v1 = ((const float4*)p)[1];
        float4 v2 = ((const float4*)p)[2];
        float4 v3 = ((const float4*)p)[3];
        int w0 = __builtin_amdgcn_cvt_pk_fp8_f32(v0.x, v0.y, 0, false);
        w0     = __builtin_amdgcn_cvt_pk_fp8_f32(v0.z, v0.w, w0, true);
        int w1 = __builtin_amdgcn_cvt_pk_fp8_f32(v1.x, v1.y, 0, false);
        w1     = __builtin_amdgcn_cvt_pk_fp8_f32(v1.z, v1.w, w1, true);
        int w2 = __builtin_amdgcn_cvt_pk_fp8_f32(v2.x, v2.y, 0, false);
        w2     = __builtin_amdgcn_cvt_pk_fp8_f32(v2.z, v2.w, w2, true);
        int w3 = __builtin_amdgcn_cvt_pk_fp8_f32(v3.x, v3.y, 0, false);
        w3     = __builtin_amdgcn_cvt_pk_fp8_f32(v3.z, v3.w, w3, true);
        int4 out = make_int4(w0, w1, w2, w3);
        const int kb = c >> 3;
        const int p8 = (c & 7) ^ (r & 7);        // XOR slot
        *(int4*)(dst + ((size_t)((r >> 7) * kTiles + kb) * 1024
                        + (size_t)(r & 127) * 8 + p8) * 16) = out;

        const int cs = c + (c >> 3);             // padded LDS slot
        if (!half) {
            Lf[urow][cs][0] = v0; Lf[urow][cs][1] = v1;
            Lf[urow][cs][2] = v2; Lf[urow][cs][3] = v3;
        }
        if (tid < 2) { S_im[b * 2 + tid] = 0.f; S_tt[b * 2 + tid] = 0.f; }
        if (b == 0 && tid < 24) red[tid] = 0.f;  // pg, lg, ticket, rowTickets
        __syncthreads();
        if (half) {
            float4 a0 = Lf[urow][cs][0], a1 = Lf[urow][cs][1];
            float4 a2 = Lf[urow][cs][2], a3 = Lf[urow][cs][3];
            float s = a0.x*v0.x + a0.y*v0.y + a0.z*v0.z + a0.w*v0.w
                    + a1.x*v1.x + a1.y*v1.y + a1.z*v1.z + a1.w*v1.w
                    + a2.x*v2.x + a2.y*v2.y + a2.z*v2.z + a2.w*v2.w
                    + a3.x*v3.x + a3.y*v3.y + a3.z*v3.z + a3.w*v3.w;
            #pragma unroll
            for (int m2 = 1; m2 < 64; m2 <<= 1) s += __shfl_xor(s, m2, 64);
            if (c == 0) {                        // one lane per row
                const float ls = logit_scale[0];
                const float inv_rw = 1.0f / (float)(Bn - 1);
                float dd = expf(-ls * s);
                coef_im[r] = dd * inv_rw / (ru_im[r] + EPSF);
                coef_tt[r] = dd * inv_rw / (ru_tt[r] + EPSF);
                p1arr[r] = l1_im[r] / (u_im[r] + EPSF)
                         + l1_tt[r] / (u_tt[r] + EPSF);
                lgarr[r] = logf(u_im[r]) + logf(u_tt[r]);
            }
        }
    } else {
        int b2 = b - nComb;
        const int isTT = (b2 >= bpm);
        const int blk  = isTT ? b2 - bpm : b2;
        const float* src = isTT ? tt : im;
        unsigned char* dst = isTT ? bTt : bIm;
        const int upr = D >> 4;                  // 64 units per row
        const int urow = tid / upr;
        const int c    = tid - urow * upr;
        const int r    = blk * (256 / upr) + urow;
        const float* p = src + (size_t)r * D + (size_t)c * 16;
        float4 v0 = ((const float4*)p)[0];
        float4 v1 = ((const float4*)p)[1];
        float4 v2 = ((const float4*)p)[2];
        float4 v3 = ((const float4*)p)[3];
        int w0 = __builtin_amdgcn_cvt_pk_fp8_f32(v0.x, v0.y, 0, false);
        w0     = __builtin_amdgcn_cvt_pk_fp8_f32(v0.z, v0.w, w0, true);
        int w1 = __builtin_amdgcn_cvt_pk_fp8_f32(v1.x, v1.y, 0, false);
        w1     = __builtin_amdgcn_cvt_pk_fp8_f32(v1.z, v1.w, w1, true);
        int w2 = __builtin_amdgcn_cvt_pk_fp8_f32(v2.x, v2.y, 0, false);
        w2     = __builtin_amdgcn_cvt_pk_fp8_f32(v2.z, v2.w, w2, true);
        int w3 = __builtin_amdgcn_cvt_pk_fp8_f32(v3.x, v3.y, 0, false);
        w3     = __builtin_amdgcn_cvt_pk_fp8_f32(v3.z, v3.w, w3, true);
        int4 out = make_int4(w0, w1, w2, w3);
        const int kb = c >> 3;
        const int p8 = (c & 7) ^ (r & 7);
        *(int4*)(dst + ((size_t)((r >> 7) * kTiles + kb) * 1024
                        + (size_t)(r & 127) * 8 + p8) * 16) = out;
    }
}

// MX-scaled fp8 GEMM, 256x256 tile, 8 waves (2M x 4N), BK=128, dbuf LDS.
// z-merged: 256 fat blocks (1/CU); free-running compiler-scheduled K-loop
// (r5 structure). Boundary = per-wave vmcnt(0) on own DMA issued a full
// tile ago + raw s_barrier.
// DISTRIBUTED fused tail (r13's serial tail cost +6.6us): per-row-group
// ticket (16 groups x 16 blocks); the group's last finisher reduces ONLY
// its 256 rows (5 KB, concurrent across groups, overlapped with other
// groups' epilogues) -> atomic partials in red[0..1]. Global ticket winner
// just combines red[0..1] into the scalar. Only 16 blocks threadfence.
__global__ __launch_bounds__(512, 2) void gemm_expsum(
    const unsigned char* __restrict__ A0, const unsigned char* __restrict__ B0,
    float* __restrict__ S0,
    const unsigned char* __restrict__ A1, const unsigned char* __restrict__ B1,
    float* __restrict__ S1,
    const float* __restrict__ logit_scale, const int* __restrict__ offset,
    const float* __restrict__ coef_im, const float* __restrict__ coef_tt,
    const float* __restrict__ p1arr, const float* __restrict__ lgarr,
    float* __restrict__ red, float* __restrict__ out,
    int Bn, int D)
{
    __shared__ unsigned char As[2][32768];   // 2 x (128-row halves), dbuf
    __shared__ unsigned char Bs[2][32768];
    __shared__ int rowLast, allLast;

    const int tid  = threadIdx.x;
    const int wave = tid >> 6;
    const int lane = tid & 63;
    const int lo   = lane & 15;
    const int qd   = lane >> 4;
    const int wm   = wave >> 2;              // 0..1  (M half)
    const int wn   = wave & 3;               // 0..3  (N quarter)
    const int offA = ((2 * qd) ^ (lo & 7)) * 16;   // first 16-B slot

    // XCD-bijective swizzle (nwg = 256, % 8 == 0).
    const int nx  = gridDim.x;
    const int nwg = nx * gridDim.y;
    int wg = blockIdx.y * nx + blockIdx.x;
    int swz = ((nwg & 7) == 0) ? ((wg & 7) * (nwg >> 3) + (wg >> 3)) : wg;
    const int by = swz / nx;
    const int bx = swz - by * nx;

    const int kTiles = D >> 7;

    // Owner staging: wave pair (wave>>1) owns one 16 KB half-tile
    // {A-h0,A-h1,B-h0,B-h1}; part = wave&1 stages 8 KB (8 x 16 B / lane).
    const int half = wave >> 1;
    const int part = wave & 1;
    const bool ownerIsA = (half < 2);
    const int ownerLoff = (half & 1) * 16384 + part * 8192;

    auto stageOwner = [&](int buf, const unsigned char* At,
                          const unsigned char* Bt, int kb) {
        const unsigned char* g =
            (ownerIsA ? At + (size_t)half * kTiles * 16384
                      : Bt + (size_t)(half - 2) * kTiles * 16384)
            + (size_t)kb * 16384 + part * 8192 + lane * 16;
        unsigned char* l = (ownerIsA ? &As[buf][0] : &Bs[buf][0]) + ownerLoff;
        #pragma unroll
        for (int q = 0; q < 8; ++q)
            __builtin_amdgcn_global_load_lds(
                (const AS_GLOBAL unsigned int*)(g + q * 1024),
                (AS_LDS unsigned int*)(l + q * 1024), 16, 0, 0);
    };

    // per-lane LDS fragment bases (r&7 == lo&7 for all ti/tj)
    const int aOff0 = wm * 16384 + lo * 128 + offA;                 // + ti*2048
    const int bOff0 = (wn >> 1) * 16384 + ((wn & 1) * 64 + lo) * 128 + offA;

    const float ls = logit_scale[0];
    const int offs = offset[0];

    for (int zz = 0; zz < 2; ++zz) {
        const unsigned char* A = zz ? A1 : A0;
        const unsigned char* B = zz ? B1 : B0;
        float* S = zz ? S1 : S0;
        const unsigned char* Atile = A + (size_t)(2 * by) * kTiles * 16384;
        const unsigned char* Btile = B + (size_t)(2 * bx) * kTiles * 16384;

        f32x4 acc[8][4];
        #pragma unroll
        for (int i = 0; i < 8; ++i)
            #pragma unroll
            for (int j = 0; j < 4; ++j)
                acc[i][j] = (f32x4){0.f, 0.f, 0.f, 0.f};

        if (zz == 0) {                       // cold prologue (z0 only)
            stageOwner(0, Atile, Btile, 0);
            asm volatile("s_waitcnt vmcnt(0)" ::: "memory");
            __builtin_amdgcn_s_barrier();
        }
        // zz==1: tile0 staged at z0's last K-tile, drained under z0's
        // epilogue; sits in buf0 (kTiles even -> parity matches).

        for (int kb = 0; kb < kTiles; ++kb) {
            const int cur = kb & 1;
            if (kb + 1 < kTiles) {
                stageOwner(1 - cur, Atile, Btile, kb + 1);
            } else if (zz == 0) {            // last z0 tile: stage z1 tile0
                stageOwner(1 - cur,
                           A1 + (size_t)(2 * by) * kTiles * 16384,
                           B1 + (size_t)(2 * bx) * kTiles * 16384, 0);
            }

            i32x8 bq[4];
            #pragma unroll
            for (int tj = 0; tj < 4; ++tj) {
                const int ba = bOff0 + tj * 2048;
                union { int4 h[2]; i32x8 v; } u;
                u.h[0] = *(const int4*)&Bs[cur][ba];
                u.h[1] = *(const int4*)&Bs[cur][ba ^ 16];
                bq[tj] = u.v;
            }

            // One scheduler region: 16 ds_read_b128 + 32 MFMA; compiler
            // interleaves with fine lgkmcnt, waves drift -> LDS || MFMA.
            #pragma unroll
            for (int ph = 0; ph < 4; ++ph) {
                const int ti0 = 2 * ph;
                union { int4 h[2]; i32x8 v; } ua0, ua1;
                {
                    const int aa0 = aOff0 + ti0 * 2048;
                    ua0.h[0] = *(const int4*)&As[cur][aa0];
                    ua0.h[1] = *(const int4*)&As[cur][aa0 ^ 16];
                    const int aa1 = aOff0 + (ti0 + 1) * 2048;
                    ua1.h[0] = *(const int4*)&As[cur][aa1];
                    ua1.h[1] = *(const int4*)&As[cur][aa1 ^ 16];
                }
                #pragma unroll
                for (int tj = 0; tj < 4; ++tj)
                    acc[ti0][tj] = __builtin_amdgcn_mfma_scale_f32_16x16x128_f8f6f4(
                        ua0.v, bq[tj], acc[ti0][tj],
                        0, 0, 0, 127, 0, 127);
                #pragma unroll
                for (int tj = 0; tj < 4; ++tj)
                    acc[ti0 + 1][tj] = __builtin_amdgcn_mfma_scale_f32_16x16x128_f8f6f4(
                        ua1.v, bq[tj], acc[ti0 + 1][tj],
                        0, 0, 0, 127, 0, 127);
            }

            if (kb + 1 < kTiles) {
                // own DMA for kb+1 issued a full tile ago: cheap drain
                asm volatile("s_waitcnt vmcnt(0)" ::: "memory");
                __builtin_amdgcn_s_barrier();
            }
        }

        // epilogue for this z; z1's tile-0 DMA (if zz==0) flies under it
        const int rowBase = by * 256 + wm * 128;
        const int colBase = bx * 256 + wn * 64;
        #pragma unroll
        for (int ti = 0; ti < 8; ++ti) {
            #pragma unroll
            for (int r = 0; r < 4; ++r) {
                int gi = rowBase + 16 * ti + 4 * qd + r; // C/D row=quad*4+reg
                float rs = 0.f;
                #pragma unroll
                for (int tj = 0; tj < 4; ++tj) {
                    int gj = colBase + 16 * tj + lo;     // C/D col=lane&15
                    float e = __expf(ls * acc[ti][tj][r]);
                    if (gj == gi + offs) e = 0.f;        // shifted diagonal
                    rs += e;
                }
                #pragma unroll
                for (int m = 1; m < 16; m <<= 1) rs += __shfl_xor(rs, m, 64);
                if (lo == 0) atomicAdd(&S[gi], rs);
            }
        }

        if (zz == 0) {                       // drain z1 tile0 before z1 loop
            asm volatile("s_waitcnt vmcnt(0)" ::: "memory");
            __builtin_amdgcn_s_barrier();
        }
    }

    // ---- distributed tail: row-group reduction, then scalar finish ----
    asm volatile("s_waitcnt vmcnt(0)" ::: "memory");  // own S atomics done
    __syncthreads();                     // all waves' atomics performed
    if (tid == 0) {
        int t = atomicAdd((int*)&red[3 + by], 1);     // row-group ticket
        rowLast = (t == nx - 1);
    }
    __syncthreads();
    if (rowLast) {
        __threadfence();                 // acquire peers' S (16 blocks only)
        float pg = 0.f, lg = 0.f;
        if (tid < 256) {
            int r = by * 256 + tid;
            pg = p1arr[r] + S0[r] * coef_im[r] + S1[r] * coef_tt[r];
            lg = lgarr[r];
        }
        float* sp = (float*)&As[0][0];   // LDS free after K-loop
        float* sl = sp + 512;
        sp[tid] = pg; sl[tid] = lg;
        __syncthreads();
        for (int s = 256; s > 0; s >>= 1) {
            if (tid < s) { sp[tid] += sp[tid + s]; sl[tid] += sl[tid + s]; }
            __syncthreads();
        }
        if (tid == 0) {
            atomicAdd(&red[0], sp[0]);
            atomicAdd(&red[1], sl[0]);
        }
    }
    asm volatile("s_waitcnt vmcnt(0)" ::: "memory");  // red adds performed
    __syncthreads();
    if (tid == 0) {
        int t = atomicAdd((int*)&red[2], 1);          // global ticket
        allLast = (t == nwg - 1);
    }
    __syncthreads();
    if (!allLast) return;
    if (tid == 0) {
        float pgSum = atomicAdd(&red[0], 0.f);        // device-coherent read
        float lgSum = atomicAdd(&red[1], 0.f);
        float loss = ((pgSum / (float)Bn) * 0.5f) / ls
                   + RHOF / ls
                   + (lgSum / (float)Bn) * 0.5f / ls;
        out[0] = loss;
    }
}

extern "C" void kernel_launch(void* const* d_in, const int* in_sizes, int n_in,
                              void* d_out, int out_size, void* d_ws, size_t ws_size,
                              hipStream_t stream) {
    const float* im    = (const float*)d_in[0];
    const float* tt    = (const float*)d_in[1];
    const float* rim   = (const float*)d_in[2];
    const float* rtt   = (const float*)d_in[3];
    const float* ru_im = (const float*)d_in[4];
    const float* ru_tt = (const float*)d_in[5];
    const float* l1_im = (const float*)d_in[6];
    const float* l1_tt = (const float*)d_in[7];
    const float* u_im  = (const float*)d_in[8];
    const float* u_tt  = (const float*)d_in[9];
    const float* lsc   = (const float*)d_in[10];
    const int*   offs  = (const int*)d_in[11];

    const int Bn = in_sizes[4];          // 4096
    const int D  = in_sizes[0] / Bn;     // 1024
    const int nComb = Bn / 2;            // rim+rtt combined blocks (2 rows)
    const int bpm = Bn * D / (256 * 16); // im/tt conversion blocks (4 rows)

    char* base = (char*)d_ws;
    float* S_im    = (float*)base;
    float* S_tt    = S_im + Bn;
    float* coef_im = S_tt + Bn;
    float* coef_tt = coef_im + Bn;
    float* p1arr   = coef_tt + Bn;
    float* lgarr   = p1arr + Bn;
    float* red     = lgarr + Bn;         // [0]=pg [1]=lg [2]=ticket [3..18]=row
    const size_t headBytes = (((size_t)(6 * Bn + 24) * sizeof(float)) + 255) & ~(size_t)255;
    const size_t matBytes  = (size_t)Bn * D;          // fp8: 1 B/elem
    unsigned char* buf0 = (unsigned char*)(base + headBytes);
    unsigned char* bRim = buf0;
    unsigned char* bTt  = buf0 + matBytes;
    unsigned char* bRtt = buf0 + 2 * matBytes;
    unsigned char* bIm  = buf0 + 3 * matBytes;

    prep_fp8<<<nComb + 2 * bpm, 256, 0, stream>>>(
        im, tt, rim, rtt, bIm, bTt, bRim, bRtt,
        S_im, S_tt, coef_im, coef_tt, p1arr, lgarr, red,
        lsc, ru_im, ru_tt, l1_im, l1_tt, u_im, u_tt,
        D, nComb, bpm, Bn);

    dim3 ggrid(Bn / 256, Bn / 256, 1);
    gemm_expsum<<<ggrid, 512, 0, stream>>>(
        bRim, bTt, S_im, bRtt, bIm, S_tt, lsc, offs,
        coef_im, coef_tt, p1arr, lgarr,
        red, (float*)d_out, Bn, D);
}